// Round 1
// baseline (309.887 us; speedup 1.0000x reference)
//
#include <hip/hip_runtime.h>

typedef __attribute__((ext_vector_type(8))) short s16x8;
typedef __attribute__((ext_vector_type(4))) float f32x4;

#define LOG2E 1.44269504088896340736f

__device__ __forceinline__ ushort f2bf(float f) {
  union { float f; unsigned int u; } c; c.f = f;
  unsigned int u = c.u + 0x7fffu + ((c.u >> 16) & 1u);
  return (ushort)(u >> 16);
}

__device__ __forceinline__ s16x8 ld16(const ushort* p) {
  union { uint4 u; s16x8 s; } c;
  c.u = *reinterpret_cast<const uint4*>(p);
  return c.s;
}

__device__ __forceinline__ f32x4 mfma16(s16x8 a, s16x8 b, f32x4 c) {
  return __builtin_amdgcn_mfma_f32_16x16x32_bf16(a, b, c, 0, 0, 0);
}

// ---------------- cast kernels ----------------

__global__ __launch_bounds__(256) void k_cast(const float* __restrict__ src,
                                              ushort* __restrict__ dst, int n) {
  int i = (blockIdx.x * 256 + threadIdx.x) * 4;
  if (i >= n) return;
  float4 v = *reinterpret_cast<const float4*>(src + i);
  ushort4 o;
  o.x = f2bf(v.x); o.y = f2bf(v.y); o.z = f2bf(v.z); o.w = f2bf(v.w);
  *reinterpret_cast<ushort4*>(dst + i) = o;
}

// src: K x N fp32 row-major ; dst: N x K bf16 row-major (transposed cast)
__global__ __launch_bounds__(256) void k_transpose_cast(const float* __restrict__ src,
                                                        ushort* __restrict__ dst,
                                                        int K, int N) {
  __shared__ float tile[32][33];
  int n0 = blockIdx.x * 32, k0 = blockIdx.y * 32;
  int tx = threadIdx.x & 31, ty = threadIdx.x >> 5;  // ty: 0..7
#pragma unroll
  for (int i = 0; i < 32; i += 8)
    tile[ty + i][tx] = src[(k0 + ty + i) * N + (n0 + tx)];
  __syncthreads();
#pragma unroll
  for (int i = 0; i < 32; i += 8)
    dst[(size_t)(n0 + ty + i) * K + (k0 + tx)] = f2bf(tile[tx][ty + i]);
}

// ---------------- GEMM helpers ----------------
// LDS tile: 128 rows x 64 cols bf16, row stride 128B, 16B chunks XOR-swizzled by (row&7)

__device__ __forceinline__ void stage_tile(const ushort* __restrict__ src, int ld, char* lds) {
  int t = threadIdx.x;
#pragma unroll
  for (int p = 0; p < 4; ++p) {
    int chunk = p * 256 + t;       // 0..1023
    int r = chunk >> 3, cc = chunk & 7;
    uint4 v = *reinterpret_cast<const uint4*>(src + r * ld + cc * 8);
    *reinterpret_cast<uint4*>(lds + r * 128 + ((cc ^ (r & 7)) * 16)) = v;
  }
}

__device__ __forceinline__ s16x8 lds_frag(const char* lds, int row, int c) {
  union { uint4 u; s16x8 s; } cv;
  cv.u = *reinterpret_cast<const uint4*>(lds + row * 128 + ((c ^ (row & 7)) * 16));
  return cv.s;
}

// ---------------- QKV GEMM ----------------
// A: xb rows mapped (stream,b,l) -> x row b*2048 + s*1024 + l ; B: Wt[n][k]
// Output: Q,K as [s][b][h][l][d] bf16 ; V transposed as [s][b][h][d][l] via swapped-operand MFMA.

template <bool TRANS>
__global__ __launch_bounds__(256) void k_gemm_qkv(
    const ushort* __restrict__ xb, const ushort* __restrict__ WtR,
    const ushort* __restrict__ WtD, const float* __restrict__ bR,
    const float* __restrict__ bD, ushort* __restrict__ Qb,
    ushort* __restrict__ Kb, ushort* __restrict__ Vt) {
  __shared__ __align__(16) char lds[32768];
  char* ldsA = lds;
  char* ldsB = lds + 16384;
  int m0 = blockIdx.x * 128;
  int n0 = (TRANS ? 1024 : 0) + blockIdx.y * 128;
  int s = m0 >> 13, bb = (m0 >> 10) & 7, lbase = m0 & 1023;
  const ushort* A = xb + (size_t)(bb * 2048 + s * 1024 + lbase) * 512;
  const ushort* Wt = (s ? WtD : WtR) + (size_t)n0 * 512;
  const float* bias = s ? bD : bR;
  int t = threadIdx.x;
  int wid = t >> 6, ln = t & 15, g = (t & 63) >> 4;
  int wr = wid >> 1, wc = wid & 1;
  f32x4 acc[4][4] = {};
  for (int ks = 0; ks < 8; ++ks) {
    __syncthreads();
    stage_tile(A + ks * 64, 512, ldsA);
    stage_tile(Wt + ks * 64, 512, ldsB);
    __syncthreads();
#pragma unroll
    for (int kk = 0; kk < 2; ++kk) {
      s16x8 af[4], bf[4];
#pragma unroll
      for (int mi = 0; mi < 4; ++mi) af[mi] = lds_frag(ldsA, wr * 64 + mi * 16 + ln, kk * 4 + g);
#pragma unroll
      for (int ni = 0; ni < 4; ++ni) bf[ni] = lds_frag(ldsB, wc * 64 + ni * 16 + ln, kk * 4 + g);
#pragma unroll
      for (int mi = 0; mi < 4; ++mi)
#pragma unroll
        for (int ni = 0; ni < 4; ++ni)
          acc[mi][ni] = TRANS ? mfma16(bf[ni], af[mi], acc[mi][ni])
                              : mfma16(af[mi], bf[ni], acc[mi][ni]);
    }
  }
  int hb_base = (s * 8 + bb) * 8;
  if (!TRANS) {
    ushort* dst = (n0 >> 9) ? Kb : Qb;
#pragma unroll
    for (int mi = 0; mi < 4; ++mi)
#pragma unroll
      for (int ni = 0; ni < 4; ++ni) {
        f32x4 v = acc[mi][ni];
        int col = n0 + wc * 64 + ni * 16 + ln;
        int h = (col >> 6) & 7, d = col & 63;
        float bv = bias[col];
        ushort* hp = dst + ((size_t)(hb_base + h) << 16);
        int lr = lbase + wr * 64 + mi * 16 + g * 4;
#pragma unroll
        for (int j = 0; j < 4; ++j) hp[(lr + j) * 64 + d] = f2bf(v[j] + bv);
      }
  } else {
#pragma unroll
    for (int mi = 0; mi < 4; ++mi)
#pragma unroll
      for (int ni = 0; ni < 4; ++ni) {
        f32x4 v = acc[mi][ni];  // Z[n][m]: row=n (g*4+j), col=m (ln)
        int nb = n0 + wc * 64 + ni * 16 + g * 4;
        int mm = m0 + wr * 64 + mi * 16 + ln;
        int l = mm & 1023;
#pragma unroll
        for (int j = 0; j < 4; ++j) {
          int col = nb + j;
          int h = (col >> 6) & 7, d = col & 63;
          Vt[((size_t)(hb_base + h) << 16) + d * 1024 + l] = f2bf(v[j] + bias[col]);
        }
      }
  }
}

// ---------------- attention ----------------
// grid (16 qblocks, 16 = pair*? , 8 batches); 256 thr = 4 waves x 16 q-rows; KV tile 64.

__global__ __launch_bounds__(256) void k_attn(const ushort* __restrict__ Qb,
                                              const ushort* __restrict__ Kb,
                                              const ushort* __restrict__ Vt,
                                              ushort* __restrict__ AO) {
  __shared__ __align__(16) char plds[8192];
  int qb = blockIdx.x;
  int pair = blockIdx.y & 1, h = blockIdx.y >> 1;
  int bb = blockIdx.z;
  int sQ = 1 - pair, sKV = pair;
  const ushort* Qp = Qb + ((size_t)((sQ * 8 + bb) * 8 + h) << 16);
  const ushort* Kp = Kb + ((size_t)((sKV * 8 + bb) * 8 + h) << 16);
  const ushort* Vp = Vt + ((size_t)((sKV * 8 + bb) * 8 + h) << 16);
  int t = threadIdx.x, w = t >> 6, ln = t & 15, g = (t & 63) >> 4;
  char* pl = plds + w * 2048;
  int qrow = qb * 64 + w * 16 + ln;
  s16x8 qf0 = ld16(Qp + qrow * 64 + g * 8);
  s16x8 qf1 = ld16(Qp + qrow * 64 + 32 + g * 8);
  const float scale = 0.125f;
  float m_[4], ls[4];
  f32x4 o[4] = {};
#pragma unroll
  for (int j = 0; j < 4; ++j) { m_[j] = -__builtin_inff(); ls[j] = 0.f; }

  for (int t0 = 0; t0 < 1024; t0 += 64) {
    f32x4 sac[4];
#pragma unroll
    for (int sub = 0; sub < 4; ++sub) {
      const ushort* kp = Kp + (t0 + sub * 16 + ln) * 64 + g * 8;
      s16x8 k0 = ld16(kp), k1 = ld16(kp + 32);
      f32x4 z = {};
      z = mfma16(qf0, k0, z);
      z = mfma16(qf1, k1, z);
      sac[sub] = z;
    }
    float tm[4], al[4], rs[4];
#pragma unroll
    for (int j = 0; j < 4; ++j)
      tm[j] = fmaxf(fmaxf(sac[0][j], sac[1][j]), fmaxf(sac[2][j], sac[3][j]));
#pragma unroll
    for (int mask = 1; mask <= 8; mask <<= 1)
#pragma unroll
      for (int j = 0; j < 4; ++j) tm[j] = fmaxf(tm[j], __shfl_xor(tm[j], mask, 64));
#pragma unroll
    for (int j = 0; j < 4; ++j) {
      tm[j] *= scale;
      float mn = fmaxf(m_[j], tm[j]);
      al[j] = exp2f((m_[j] - mn) * LOG2E);
      m_[j] = mn;
      rs[j] = 0.f;
    }
#pragma unroll
    for (int sub = 0; sub < 4; ++sub)
#pragma unroll
      for (int j = 0; j < 4; ++j) {
        float p = exp2f((sac[sub][j] * scale - m_[j]) * LOG2E);
        rs[j] += p;
        int row = g * 4 + j, key = ln + sub * 16;
        *reinterpret_cast<ushort*>(pl + row * 128 + (((key >> 3) ^ (row & 7)) * 16) +
                                   (key & 7) * 2) = f2bf(p);
      }
#pragma unroll
    for (int mask = 1; mask <= 8; mask <<= 1)
#pragma unroll
      for (int j = 0; j < 4; ++j) rs[j] += __shfl_xor(rs[j], mask, 64);
#pragma unroll
    for (int j = 0; j < 4; ++j) ls[j] = ls[j] * al[j] + rs[j];
#pragma unroll
    for (int dsub = 0; dsub < 4; ++dsub)
#pragma unroll
      for (int j = 0; j < 4; ++j) o[dsub][j] *= al[j];
    s16x8 pf0 = lds_frag(pl, ln, g);
    s16x8 pf1 = lds_frag(pl, ln, 4 + g);
#pragma unroll
    for (int dsub = 0; dsub < 4; ++dsub) {
      const ushort* vp = Vp + (dsub * 16 + ln) * 1024 + t0 + g * 8;
      s16x8 v0 = ld16(vp), v1 = ld16(vp + 32);
      o[dsub] = mfma16(pf0, v0, o[dsub]);
      o[dsub] = mfma16(pf1, v1, o[dsub]);
    }
  }
  int orow = bb * 2048 + pair * 1024 + qb * 64 + w * 16 + g * 4;
#pragma unroll
  for (int j = 0; j < 4; ++j) {
    float inv = 1.0f / ls[j];
#pragma unroll
    for (int dsub = 0; dsub < 4; ++dsub)
      AO[(size_t)(orow + j) * 512 + h * 64 + dsub * 16 + ln] = f2bf(o[dsub][j] * inv);
  }
}

// ---------------- output projection GEMM ----------------

__global__ __launch_bounds__(256) void k_gemm_proj(const ushort* __restrict__ AO,
                                                   const ushort* __restrict__ WtP,
                                                   const float* __restrict__ bP,
                                                   float* __restrict__ Out) {
  __shared__ __align__(16) char lds[32768];
  char* ldsA = lds;
  char* ldsB = lds + 16384;
  int m0 = blockIdx.x * 128, n0 = blockIdx.y * 128;
  const ushort* A = AO + (size_t)m0 * 512;
  const ushort* Wt = WtP + (size_t)n0 * 512;
  int t = threadIdx.x;
  int wid = t >> 6, ln = t & 15, g = (t & 63) >> 4;
  int wr = wid >> 1, wc = wid & 1;
  f32x4 acc[4][4] = {};
  for (int ks = 0; ks < 8; ++ks) {
    __syncthreads();
    stage_tile(A + ks * 64, 512, ldsA);
    stage_tile(Wt + ks * 64, 512, ldsB);
    __syncthreads();
#pragma unroll
    for (int kk = 0; kk < 2; ++kk) {
      s16x8 af[4], bf[4];
#pragma unroll
      for (int mi = 0; mi < 4; ++mi) af[mi] = lds_frag(ldsA, wr * 64 + mi * 16 + ln, kk * 4 + g);
#pragma unroll
      for (int ni = 0; ni < 4; ++ni) bf[ni] = lds_frag(ldsB, wc * 64 + ni * 16 + ln, kk * 4 + g);
#pragma unroll
      for (int mi = 0; mi < 4; ++mi)
#pragma unroll
        for (int ni = 0; ni < 4; ++ni) acc[mi][ni] = mfma16(af[mi], bf[ni], acc[mi][ni]);
    }
  }
#pragma unroll
  for (int mi = 0; mi < 4; ++mi)
#pragma unroll
    for (int ni = 0; ni < 4; ++ni) {
      f32x4 v = acc[mi][ni];
      int col = n0 + wc * 64 + ni * 16 + ln;
      float bv = bP[col];
      int r0 = m0 + wr * 64 + mi * 16 + g * 4;
#pragma unroll
      for (int j = 0; j < 4; ++j) Out[(size_t)(r0 + j) * 512 + col] = v[j] + bv;
    }
}

// ---------------- launch ----------------

extern "C" void kernel_launch(void* const* d_in, const int* in_sizes, int n_in,
                              void* d_out, int out_size, void* d_ws, size_t ws_size,
                              hipStream_t stream) {
  const float* x      = (const float*)d_in[0];
  const float* W_rgb  = (const float*)d_in[1];
  const float* b_rgb  = (const float*)d_in[2];
  const float* W_dep  = (const float*)d_in[3];
  const float* b_dep  = (const float*)d_in[4];
  const float* W_proj = (const float*)d_in[5];
  const float* b_proj = (const float*)d_in[6];
  float* out = (float*)d_out;

  char* ws = (char*)d_ws;
  ushort* xb  = (ushort*)(ws + 0);          // 8,388,608 el bf16 = 16 MB
  ushort* WtR = (ushort*)(ws + 16777216);   // 1536x512
  ushort* WtD = (ushort*)(ws + 18350080);
  ushort* WtP = (ushort*)(ws + 19922944);   // 512x512
  ushort* Qb  = (ushort*)(ws + 20447232);   // [2][8][8][1024][64]
  ushort* Kb  = (ushort*)(ws + 37224448);
  ushort* Vt  = (ushort*)(ws + 54001664);   // [2][8][8][64][1024]
  ushort* AO  = (ushort*)(ws + 70778880);   // [16384][512]

  k_cast<<<8192, 256, 0, stream>>>(x, xb, 8388608);
  k_transpose_cast<<<dim3(48, 16), 256, 0, stream>>>(W_rgb, WtR, 512, 1536);
  k_transpose_cast<<<dim3(48, 16), 256, 0, stream>>>(W_dep, WtD, 512, 1536);
  k_transpose_cast<<<dim3(16, 16), 256, 0, stream>>>(W_proj, WtP, 512, 512);
  k_gemm_qkv<false><<<dim3(128, 8), 256, 0, stream>>>(xb, WtR, WtD, b_rgb, b_dep, Qb, Kb, Vt);
  k_gemm_qkv<true><<<dim3(128, 4), 256, 0, stream>>>(xb, WtR, WtD, b_rgb, b_dep, Qb, Kb, Vt);
  k_attn<<<dim3(16, 16, 8), 256, 0, stream>>>(Qb, Kb, Vt, AO);
  k_gemm_proj<<<dim3(128, 4), 256, 0, stream>>>(AO, WtP, b_proj, out);
}

// Round 3
// 307.456 us; speedup vs baseline: 1.0079x; 1.0079x over previous
//
#include <hip/hip_runtime.h>
#include <hip/hip_bf16.h>

typedef __attribute__((ext_vector_type(8))) short s16x8;
typedef __attribute__((ext_vector_type(4))) float f32x4;

__device__ __forceinline__ ushort f2bf(float f) {
  union { float f; unsigned int u; } c; c.f = f;
  unsigned int u = c.u + 0x7fffu + ((c.u >> 16) & 1u);
  return (ushort)(u >> 16);
}

__device__ __forceinline__ unsigned int pack2(float lo, float hi) {
  __hip_bfloat162 b2 = __float22bfloat162_rn(make_float2(lo, hi));
  union { __hip_bfloat162 b; unsigned int u; } c; c.b = b2;
  return c.u;
}

__device__ __forceinline__ s16x8 ld16(const ushort* p) {
  union { uint4 u; s16x8 s; } c;
  c.u = *reinterpret_cast<const uint4*>(p);
  return c.s;
}

__device__ __forceinline__ f32x4 mfma16(s16x8 a, s16x8 b, f32x4 c) {
  return __builtin_amdgcn_mfma_f32_16x16x32_bf16(a, b, c, 0, 0, 0);
}

__device__ __forceinline__ float exp2fast(float x) { return __builtin_amdgcn_exp2f(x); }

// ---------------- cast kernels ----------------

__global__ __launch_bounds__(256) void k_cast(const float* __restrict__ src,
                                              ushort* __restrict__ dst, int n) {
  int i = (blockIdx.x * 256 + threadIdx.x) * 4;
  if (i >= n) return;
  float4 v = *reinterpret_cast<const float4*>(src + i);
  ushort4 o;
  o.x = f2bf(v.x); o.y = f2bf(v.y); o.z = f2bf(v.z); o.w = f2bf(v.w);
  *reinterpret_cast<ushort4*>(dst + i) = o;
}

__global__ __launch_bounds__(256) void k_transpose_cast(const float* __restrict__ src,
                                                        ushort* __restrict__ dst,
                                                        int K, int N) {
  __shared__ float tile[32][33];
  int n0 = blockIdx.x * 32, k0 = blockIdx.y * 32;
  int tx = threadIdx.x & 31, ty = threadIdx.x >> 5;
#pragma unroll
  for (int i = 0; i < 32; i += 8)
    tile[ty + i][tx] = src[(k0 + ty + i) * N + (n0 + tx)];
  __syncthreads();
#pragma unroll
  for (int i = 0; i < 32; i += 8)
    dst[(size_t)(n0 + ty + i) * K + (k0 + tx)] = f2bf(tile[tx][ty + i]);
}

// ---------------- GEMM helpers ----------------

__device__ __forceinline__ void stage_tile(const ushort* __restrict__ src, int ld, char* lds) {
  int t = threadIdx.x;
#pragma unroll
  for (int p = 0; p < 4; ++p) {
    int chunk = p * 256 + t;
    int r = chunk >> 3, cc = chunk & 7;
    uint4 v = *reinterpret_cast<const uint4*>(src + r * ld + cc * 8);
    *reinterpret_cast<uint4*>(lds + r * 128 + ((cc ^ (r & 7)) * 16)) = v;
  }
}

__device__ __forceinline__ s16x8 lds_frag(const char* lds, int row, int c) {
  union { uint4 u; s16x8 s; } cv;
  cv.u = *reinterpret_cast<const uint4*>(lds + row * 128 + ((c ^ (row & 7)) * 16));
  return cv.s;
}

// ---------------- QKV GEMM ----------------
// Q pre-scaled by softmax_scale*log2(e); V stored phi-permuted within 64-key tiles.

template <bool TRANS>
__global__ __launch_bounds__(256) void k_gemm_qkv(
    const ushort* __restrict__ xb, const ushort* __restrict__ WtR,
    const ushort* __restrict__ WtD, const float* __restrict__ bR,
    const float* __restrict__ bD, ushort* __restrict__ Qb,
    ushort* __restrict__ Kb, ushort* __restrict__ Vt) {
  __shared__ __align__(16) char lds[32768];
  char* ldsA = lds;
  char* ldsB = lds + 16384;
  int m0 = blockIdx.x * 128;
  int n0 = (TRANS ? 1024 : 0) + blockIdx.y * 128;
  int s = m0 >> 13, bb = (m0 >> 10) & 7, lbase = m0 & 1023;
  const ushort* A = xb + (size_t)(bb * 2048 + s * 1024 + lbase) * 512;
  const ushort* Wt = (s ? WtD : WtR) + (size_t)n0 * 512;
  const float* bias = s ? bD : bR;
  int t = threadIdx.x;
  int wid = t >> 6, ln = t & 15, g = (t & 63) >> 4;
  int wr = wid >> 1, wc = wid & 1;
  f32x4 acc[4][4] = {};
  for (int ks = 0; ks < 8; ++ks) {
    __syncthreads();
    stage_tile(A + ks * 64, 512, ldsA);
    stage_tile(Wt + ks * 64, 512, ldsB);
    __syncthreads();
#pragma unroll
    for (int kk = 0; kk < 2; ++kk) {
      s16x8 af[4], bf[4];
#pragma unroll
      for (int mi = 0; mi < 4; ++mi) af[mi] = lds_frag(ldsA, wr * 64 + mi * 16 + ln, kk * 4 + g);
#pragma unroll
      for (int ni = 0; ni < 4; ++ni) bf[ni] = lds_frag(ldsB, wc * 64 + ni * 16 + ln, kk * 4 + g);
#pragma unroll
      for (int mi = 0; mi < 4; ++mi)
#pragma unroll
        for (int ni = 0; ni < 4; ++ni)
          acc[mi][ni] = TRANS ? mfma16(bf[ni], af[mi], acc[mi][ni])
                              : mfma16(af[mi], bf[ni], acc[mi][ni]);
    }
  }
  int hb_base = (s * 8 + bb) * 8;
  if (!TRANS) {
    bool isK = (n0 >> 9) != 0;
    ushort* dst = isK ? Kb : Qb;
    float sc = isK ? 1.0f : 0.18033688011112042f;  // 0.125 * log2(e)
#pragma unroll
    for (int mi = 0; mi < 4; ++mi)
#pragma unroll
      for (int ni = 0; ni < 4; ++ni) {
        f32x4 v = acc[mi][ni];
        int col = n0 + wc * 64 + ni * 16 + ln;
        int h = (col >> 6) & 7, d = col & 63;
        float bv = bias[col];
        ushort* hp = dst + ((size_t)(hb_base + h) << 16);
        int lr = lbase + wr * 64 + mi * 16 + g * 4;
#pragma unroll
        for (int j = 0; j < 4; ++j) hp[(lr + j) * 64 + d] = f2bf((v[j] + bv) * sc);
      }
  } else {
#pragma unroll
    for (int mi = 0; mi < 4; ++mi)
#pragma unroll
      for (int ni = 0; ni < 4; ++ni) {
        f32x4 v = acc[mi][ni];
        int nb = n0 + wc * 64 + ni * 16 + g * 4;
        int mm = m0 + wr * 64 + mi * 16 + ln;
        int l = mm & 1023;
        // phi permute within 64-key tile: keep bits 5,1,0; b4->b2; b3:2->b4:3
        int lp = (l & ~63) | (l & 0x23) | ((l & 0x0C) << 1) | ((l & 0x10) >> 2);
#pragma unroll
        for (int j = 0; j < 4; ++j) {
          int col = nb + j;
          int h = (col >> 6) & 7, d = col & 63;
          Vt[((size_t)(hb_base + h) << 16) + d * 1024 + lp] = f2bf(v[j] + bias[col]);
        }
      }
  }
}

// ---------------- attention (swapped-operand, LDS-free) ----------------
// 4 waves x 16 q-rows; KV tile 64. Lane (g,ln): q=ln, keys 16s+4g+r in z[s][r].

__global__ __launch_bounds__(256) void k_attn(const ushort* __restrict__ Qb,
                                              const ushort* __restrict__ Kb,
                                              const ushort* __restrict__ Vt,
                                              ushort* __restrict__ AO) {
  int qb = blockIdx.x;
  int pair = blockIdx.y & 1, h = blockIdx.y >> 1;
  int bb = blockIdx.z;
  int sQ = 1 - pair, sKV = pair;
  const ushort* Qp = Qb + ((size_t)((sQ * 8 + bb) * 8 + h) << 16);
  const ushort* Kp = Kb + ((size_t)((sKV * 8 + bb) * 8 + h) << 16);
  const ushort* Vp = Vt + ((size_t)((sKV * 8 + bb) * 8 + h) << 16);
  int t = threadIdx.x, w = t >> 6, ln = t & 15, g = (t & 63) >> 4;
  int q0 = qb * 64 + w * 16;
  s16x8 qf0 = ld16(Qp + (q0 + ln) * 64 + g * 8);
  s16x8 qf1 = ld16(Qp + (q0 + ln) * 64 + 32 + g * 8);
  float m_ = -1.0e30f;
  float ls = 0.f;
  f32x4 oc[4] = {};

  for (int t0 = 0; t0 < 1024; t0 += 64) {
    f32x4 z[4];
#pragma unroll
    for (int s = 0; s < 4; ++s) {
      const ushort* kp = Kp + (t0 + s * 16 + ln) * 64 + g * 8;
      s16x8 k0 = ld16(kp), k1 = ld16(kp + 32);
      f32x4 zz = {};
      zz = mfma16(k0, qf0, zz);
      zz = mfma16(k1, qf1, zz);
      z[s] = zz;
    }
    // per-lane (per-g) tile max only; cross-lane reduce deferred to rescale path
    float a0 = fmaxf(fmaxf(z[0][0], z[0][1]), fmaxf(z[0][2], z[0][3]));
    float a1 = fmaxf(fmaxf(z[1][0], z[1][1]), fmaxf(z[1][2], z[1][3]));
    float a2 = fmaxf(fmaxf(z[2][0], z[2][1]), fmaxf(z[2][2], z[2][3]));
    float a3 = fmaxf(fmaxf(z[3][0], z[3][1]), fmaxf(z[3][2], z[3][3]));
    float tmg = fmaxf(fmaxf(a0, a1), fmaxf(a2, a3));
    if (__any(tmg > m_ + 8.0f)) {
      // rare path: full cross-g max, rescale running state
      float tm = tmg;
      tm = fmaxf(tm, __shfl_xor(tm, 16, 64));
      tm = fmaxf(tm, __shfl_xor(tm, 32, 64));
      float mnew = fmaxf(m_, tm);
      float al = exp2fast(m_ - mnew);
      m_ = mnew;
      ls *= al;
#pragma unroll
      for (int dsub = 0; dsub < 4; ++dsub) oc[dsub] = oc[dsub] * al;
    }
    unsigned int pw[8];
#pragma unroll
    for (int s = 0; s < 4; ++s) {
      float p0 = exp2fast(z[s][0] - m_);
      float p1 = exp2fast(z[s][1] - m_);
      float p2 = exp2fast(z[s][2] - m_);
      float p3 = exp2fast(z[s][3] - m_);
      ls += (p0 + p1) + (p2 + p3);
      pw[2 * s] = pack2(p0, p1);
      pw[2 * s + 1] = pack2(p2, p3);
    }
    union { uint4 u; s16x8 v; } pf0c, pf1c;
    pf0c.u = make_uint4(pw[0], pw[1], pw[2], pw[3]);
    pf1c.u = make_uint4(pw[4], pw[5], pw[6], pw[7]);
    s16x8 pf0 = pf0c.v, pf1 = pf1c.v;
#pragma unroll
    for (int dsub = 0; dsub < 4; ++dsub) {
      const ushort* vp = Vp + (dsub * 16 + ln) * 1024 + t0;
      s16x8 v0 = ld16(vp + g * 8);
      s16x8 v1 = ld16(vp + 32 + g * 8);
      oc[dsub] = mfma16(v0, pf0, oc[dsub]);
      oc[dsub] = mfma16(v1, pf1, oc[dsub]);
    }
  }
  // combine ls across the 4 g-groups (per-lane partials -> uniform per q-row)
  ls += __shfl_xor(ls, 16, 64);
  ls += __shfl_xor(ls, 32, 64);
  float inv = 1.0f / ls;
  int orow = bb * 2048 + pair * 1024 + q0 + ln;
#pragma unroll
  for (int dsub = 0; dsub < 4; ++dsub) {
    uint2 st;
    st.x = pack2(oc[dsub][0] * inv, oc[dsub][1] * inv);
    st.y = pack2(oc[dsub][2] * inv, oc[dsub][3] * inv);
    *reinterpret_cast<uint2*>(AO + (size_t)orow * 512 + h * 64 + dsub * 16 + 4 * g) = st;
  }
}

// ---------------- output projection GEMM ----------------

__global__ __launch_bounds__(256) void k_gemm_proj(const ushort* __restrict__ AO,
                                                   const ushort* __restrict__ WtP,
                                                   const float* __restrict__ bP,
                                                   float* __restrict__ Out) {
  __shared__ __align__(16) char lds[32768];
  char* ldsA = lds;
  char* ldsB = lds + 16384;
  int m0 = blockIdx.x * 128, n0 = blockIdx.y * 128;
  const ushort* A = AO + (size_t)m0 * 512;
  const ushort* Wt = WtP + (size_t)n0 * 512;
  int t = threadIdx.x;
  int wid = t >> 6, ln = t & 15, g = (t & 63) >> 4;
  int wr = wid >> 1, wc = wid & 1;
  f32x4 acc[4][4] = {};
  for (int ks = 0; ks < 8; ++ks) {
    __syncthreads();
    stage_tile(A + ks * 64, 512, ldsA);
    stage_tile(Wt + ks * 64, 512, ldsB);
    __syncthreads();
#pragma unroll
    for (int kk = 0; kk < 2; ++kk) {
      s16x8 af[4], bf[4];
#pragma unroll
      for (int mi = 0; mi < 4; ++mi) af[mi] = lds_frag(ldsA, wr * 64 + mi * 16 + ln, kk * 4 + g);
#pragma unroll
      for (int ni = 0; ni < 4; ++ni) bf[ni] = lds_frag(ldsB, wc * 64 + ni * 16 + ln, kk * 4 + g);
#pragma unroll
      for (int mi = 0; mi < 4; ++mi)
#pragma unroll
        for (int ni = 0; ni < 4; ++ni) acc[mi][ni] = mfma16(af[mi], bf[ni], acc[mi][ni]);
    }
  }
#pragma unroll
  for (int mi = 0; mi < 4; ++mi)
#pragma unroll
    for (int ni = 0; ni < 4; ++ni) {
      f32x4 v = acc[mi][ni];
      int col = n0 + wc * 64 + ni * 16 + ln;
      float bv = bP[col];
      int r0 = m0 + wr * 64 + mi * 16 + g * 4;
#pragma unroll
      for (int j = 0; j < 4; ++j) Out[(size_t)(r0 + j) * 512 + col] = v[j] + bv;
    }
}

// ---------------- launch ----------------

extern "C" void kernel_launch(void* const* d_in, const int* in_sizes, int n_in,
                              void* d_out, int out_size, void* d_ws, size_t ws_size,
                              hipStream_t stream) {
  const float* x      = (const float*)d_in[0];
  const float* W_rgb  = (const float*)d_in[1];
  const float* b_rgb  = (const float*)d_in[2];
  const float* W_dep  = (const float*)d_in[3];
  const float* b_dep  = (const float*)d_in[4];
  const float* W_proj = (const float*)d_in[5];
  const float* b_proj = (const float*)d_in[6];
  float* out = (float*)d_out;

  char* ws = (char*)d_ws;
  ushort* xb  = (ushort*)(ws + 0);
  ushort* WtR = (ushort*)(ws + 16777216);
  ushort* WtD = (ushort*)(ws + 18350080);
  ushort* WtP = (ushort*)(ws + 19922944);
  ushort* Qb  = (ushort*)(ws + 20447232);
  ushort* Kb  = (ushort*)(ws + 37224448);
  ushort* Vt  = (ushort*)(ws + 54001664);
  ushort* AO  = (ushort*)(ws + 70778880);

  k_cast<<<8192, 256, 0, stream>>>(x, xb, 8388608);
  k_transpose_cast<<<dim3(48, 16), 256, 0, stream>>>(W_rgb, WtR, 512, 1536);
  k_transpose_cast<<<dim3(48, 16), 256, 0, stream>>>(W_dep, WtD, 512, 1536);
  k_transpose_cast<<<dim3(16, 16), 256, 0, stream>>>(W_proj, WtP, 512, 512);
  k_gemm_qkv<false><<<dim3(128, 8), 256, 0, stream>>>(xb, WtR, WtD, b_rgb, b_dep, Qb, Kb, Vt);
  k_gemm_qkv<true><<<dim3(128, 4), 256, 0, stream>>>(xb, WtR, WtD, b_rgb, b_dep, Qb, Kb, Vt);
  k_attn<<<dim3(16, 16, 8), 256, 0, stream>>>(Qb, Kb, Vt, AO);
  k_gemm_proj<<<dim3(128, 4), 256, 0, stream>>>(AO, WtP, b_proj, out);
}

// Round 4
// 138.350 us; speedup vs baseline: 2.2399x; 2.2223x over previous
//
#include <hip/hip_runtime.h>
#include <hip/hip_bf16.h>

typedef __attribute__((ext_vector_type(8))) short s16x8;
typedef __attribute__((ext_vector_type(4))) float f32x4;

__device__ __forceinline__ ushort f2bf(float f) {
  union { float f; unsigned int u; } c; c.f = f;
  unsigned int u = c.u + 0x7fffu + ((c.u >> 16) & 1u);
  return (ushort)(u >> 16);
}

__device__ __forceinline__ unsigned int pack2(float lo, float hi) {
  __hip_bfloat162 b2 = __float22bfloat162_rn(make_float2(lo, hi));
  union { __hip_bfloat162 b; unsigned int u; } c; c.b = b2;
  return c.u;
}

__device__ __forceinline__ s16x8 ld16(const ushort* p) {
  union { uint4 u; s16x8 s; } c;
  c.u = *reinterpret_cast<const uint4*>(p);
  return c.s;
}

__device__ __forceinline__ f32x4 mfma16(s16x8 a, s16x8 b, f32x4 c) {
  return __builtin_amdgcn_mfma_f32_16x16x32_bf16(a, b, c, 0, 0, 0);
}

__device__ __forceinline__ float exp2fast(float x) { return __builtin_amdgcn_exp2f(x); }

__device__ __forceinline__ void gld_lds16(const void* g, void* l) {
  __builtin_amdgcn_global_load_lds(
      (const __attribute__((address_space(1))) void*)g,
      (__attribute__((address_space(3))) void*)l, 16, 0, 0);
}

__device__ __forceinline__ float vmax4(f32x4 v) {
  return fmaxf(fmaxf(v[0], v[1]), fmaxf(v[2], v[3]));
}

// ---------------- cast kernels ----------------

__global__ __launch_bounds__(256) void k_cast(const float* __restrict__ src,
                                              ushort* __restrict__ dst, int n) {
  int i = (blockIdx.x * 256 + threadIdx.x) * 4;
  if (i >= n) return;
  float4 v = *reinterpret_cast<const float4*>(src + i);
  ushort4 o;
  o.x = f2bf(v.x); o.y = f2bf(v.y); o.z = f2bf(v.z); o.w = f2bf(v.w);
  *reinterpret_cast<ushort4*>(dst + i) = o;
}

__global__ __launch_bounds__(256) void k_transpose_cast(const float* __restrict__ src,
                                                        ushort* __restrict__ dst,
                                                        int K, int N) {
  __shared__ float tile[32][33];
  int n0 = blockIdx.x * 32, k0 = blockIdx.y * 32;
  int tx = threadIdx.x & 31, ty = threadIdx.x >> 5;
#pragma unroll
  for (int i = 0; i < 32; i += 8)
    tile[ty + i][tx] = src[(k0 + ty + i) * N + (n0 + tx)];
  __syncthreads();
#pragma unroll
  for (int i = 0; i < 32; i += 8)
    dst[(size_t)(n0 + ty + i) * K + (k0 + tx)] = f2bf(tile[tx][ty + i]);
}

// ---------------- GEMM helpers ----------------

__device__ __forceinline__ void stage_tile(const ushort* __restrict__ src, int ld, char* lds) {
  int t = threadIdx.x;
#pragma unroll
  for (int p = 0; p < 4; ++p) {
    int chunk = p * 256 + t;
    int r = chunk >> 3, cc = chunk & 7;
    uint4 v = *reinterpret_cast<const uint4*>(src + r * ld + cc * 8);
    *reinterpret_cast<uint4*>(lds + r * 128 + ((cc ^ (r & 7)) * 16)) = v;
  }
}

__device__ __forceinline__ s16x8 lds_frag(const char* lds, int row, int c) {
  union { uint4 u; s16x8 s; } cv;
  cv.u = *reinterpret_cast<const uint4*>(lds + row * 128 + ((c ^ (row & 7)) * 16));
  return cv.s;
}

// ---------------- QKV GEMM ----------------
// Q pre-scaled by softmax_scale*log2(e); V stored phi-permuted within 64-key tiles.

template <bool TRANS>
__global__ __launch_bounds__(256) void k_gemm_qkv(
    const ushort* __restrict__ xb, const ushort* __restrict__ WtR,
    const ushort* __restrict__ WtD, const float* __restrict__ bR,
    const float* __restrict__ bD, ushort* __restrict__ Qb,
    ushort* __restrict__ Kb, ushort* __restrict__ Vt) {
  __shared__ __align__(16) char lds[32768];
  char* ldsA = lds;
  char* ldsB = lds + 16384;
  int m0 = blockIdx.x * 128;
  int n0 = (TRANS ? 1024 : 0) + blockIdx.y * 128;
  int s = m0 >> 13, bb = (m0 >> 10) & 7, lbase = m0 & 1023;
  const ushort* A = xb + (size_t)(bb * 2048 + s * 1024 + lbase) * 512;
  const ushort* Wt = (s ? WtD : WtR) + (size_t)n0 * 512;
  const float* bias = s ? bD : bR;
  int t = threadIdx.x;
  int wid = t >> 6, ln = t & 15, g = (t & 63) >> 4;
  int wr = wid >> 1, wc = wid & 1;
  f32x4 acc[4][4] = {};
  for (int ks = 0; ks < 8; ++ks) {
    __syncthreads();
    stage_tile(A + ks * 64, 512, ldsA);
    stage_tile(Wt + ks * 64, 512, ldsB);
    __syncthreads();
#pragma unroll
    for (int kk = 0; kk < 2; ++kk) {
      s16x8 af[4], bf[4];
#pragma unroll
      for (int mi = 0; mi < 4; ++mi) af[mi] = lds_frag(ldsA, wr * 64 + mi * 16 + ln, kk * 4 + g);
#pragma unroll
      for (int ni = 0; ni < 4; ++ni) bf[ni] = lds_frag(ldsB, wc * 64 + ni * 16 + ln, kk * 4 + g);
#pragma unroll
      for (int mi = 0; mi < 4; ++mi)
#pragma unroll
        for (int ni = 0; ni < 4; ++ni)
          acc[mi][ni] = TRANS ? mfma16(bf[ni], af[mi], acc[mi][ni])
                              : mfma16(af[mi], bf[ni], acc[mi][ni]);
    }
  }
  int hb_base = (s * 8 + bb) * 8;
  if (!TRANS) {
    bool isK = (n0 >> 9) != 0;
    ushort* dst = isK ? Kb : Qb;
    float sc = isK ? 1.0f : 0.18033688011112042f;  // 0.125 * log2(e)
#pragma unroll
    for (int mi = 0; mi < 4; ++mi)
#pragma unroll
      for (int ni = 0; ni < 4; ++ni) {
        f32x4 v = acc[mi][ni];
        int col = n0 + wc * 64 + ni * 16 + ln;
        int h = (col >> 6) & 7, d = col & 63;
        float bv = bias[col];
        ushort* hp = dst + ((size_t)(hb_base + h) << 16);
        int lr = lbase + wr * 64 + mi * 16 + g * 4;
#pragma unroll
        for (int j = 0; j < 4; ++j) hp[(lr + j) * 64 + d] = f2bf((v[j] + bv) * sc);
      }
  } else {
#pragma unroll
    for (int mi = 0; mi < 4; ++mi)
#pragma unroll
      for (int ni = 0; ni < 4; ++ni) {
        f32x4 v = acc[mi][ni];
        int nb = n0 + wc * 64 + ni * 16 + g * 4;
        int mm = m0 + wr * 64 + mi * 16 + ln;
        int l = mm & 1023;
        // phi permute within 64-key tile: keep bits 5,1,0; b4->b2; b3:2->b4:3
        int lp = (l & ~63) | (l & 0x23) | ((l & 0x0C) << 1) | ((l & 0x10) >> 2);
#pragma unroll
        for (int j = 0; j < 4; ++j) {
          int col = nb + j;
          int h = (col >> 6) & 7, d = col & 63;
          Vt[((size_t)(hb_base + h) << 16) + d * 1024 + lp] = f2bf(v[j] + bias[col]);
        }
      }
  }
}

// ---------------- attention (LDS-staged K/V, double-buffered, 32 q/wave) ----------------
// Block: 4 waves x 32 q-rows = 128 q-rows. KV tile 64 keys.
// LDS buffer (x2): K tile 8KB [64 key-rows][64 d] + V tile 8KB [64 d-rows][64 keys(phi)]
// staged linearly via global_load_lds with inverse-XOR-swizzled global source.

__global__ __launch_bounds__(256, 4) void k_attn(const ushort* __restrict__ Qb,
                                                 const ushort* __restrict__ Kb,
                                                 const ushort* __restrict__ Vt,
                                                 ushort* __restrict__ AO) {
  __shared__ __align__(16) char lds[32768];
  int qb = blockIdx.x;                    // 0..7
  int pair = blockIdx.y & 1, h = blockIdx.y >> 1;
  int bb = blockIdx.z;
  int sQ = 1 - pair, sKV = pair;
  const ushort* Qp = Qb + ((size_t)((sQ * 8 + bb) * 8 + h) << 16);
  const ushort* Kp = Kb + ((size_t)((sKV * 8 + bb) * 8 + h) << 16);
  const ushort* Vp = Vt + ((size_t)((sKV * 8 + bb) * 8 + h) << 16);
  int t = threadIdx.x, w = t >> 6, l = t & 63, ln = t & 15, g = (t & 63) >> 4;
  int q0 = qb * 128 + w * 32;
  s16x8 qf0a = ld16(Qp + (q0 + ln) * 64 + g * 8);
  s16x8 qf1a = ld16(Qp + (q0 + ln) * 64 + 32 + g * 8);
  s16x8 qf0b = ld16(Qp + (q0 + 16 + ln) * 64 + g * 8);
  s16x8 qf1b = ld16(Qp + (q0 + 16 + ln) * 64 + 32 + g * 8);

  // staging: wave w handles chunks w*128 .. w*128+127 of each 512-chunk (8KB) tile
  int cA = w * 128 + l;          // round 0 chunk
  int cB = w * 128 + 64 + l;     // round 1 chunk
  int rA = cA >> 3, ccA = cA & 7;
  int rB = cB >> 3, ccB = cB & 7;
  int kofA = rA * 64 + ((ccA ^ (rA & 7)) * 8);   // ushort offset within K tile row-space
  int kofB = rB * 64 + ((ccB ^ (rB & 7)) * 8);
  int vofA = rA * 1024 + ((ccA ^ (rA & 7)) * 8); // ushort offset within V d-row space
  int vofB = rB * 1024 + ((ccB ^ (rB & 7)) * 8);

  float m_a = -1.0e30f, m_b = -1.0e30f, ls_a = 0.f, ls_b = 0.f;
  f32x4 oca[4] = {}, ocb[4] = {};

  // prologue: stage tile 0 into buffer 0
  {
    char* base = lds;
    gld_lds16(Kp + kofA, base + w * 2048);
    gld_lds16(Kp + kofB, base + w * 2048 + 1024);
    gld_lds16(Vp + vofA, base + 8192 + w * 2048);
    gld_lds16(Vp + vofB, base + 8192 + w * 2048 + 1024);
  }
  __syncthreads();

  int cur = 0;
  for (int it = 0; it < 16; ++it) {
    int t0 = it * 64;
    if (it < 15) {
      char* base = lds + (cur ^ 1) * 16384;
      const ushort* kp = Kp + (t0 + 64) * 64;
      const ushort* vp = Vp + (t0 + 64);
      gld_lds16(kp + kofA, base + w * 2048);
      gld_lds16(kp + kofB, base + w * 2048 + 1024);
      gld_lds16(vp + vofA, base + 8192 + w * 2048);
      gld_lds16(vp + vofB, base + 8192 + w * 2048 + 1024);
    }
    const char* ldsK = lds + cur * 16384;
    const char* ldsV = ldsK + 8192;

    f32x4 za[4], zb[4];
#pragma unroll
    for (int s = 0; s < 4; ++s) {
      s16x8 k0 = lds_frag(ldsK, s * 16 + ln, g);
      s16x8 k1 = lds_frag(ldsK, s * 16 + ln, 4 + g);
      f32x4 z1 = {}; z1 = mfma16(k0, qf0a, z1); z1 = mfma16(k1, qf1a, z1); za[s] = z1;
      f32x4 z2 = {}; z2 = mfma16(k0, qf0b, z2); z2 = mfma16(k1, qf1b, z2); zb[s] = z2;
    }

    float tma = fmaxf(fmaxf(vmax4(za[0]), vmax4(za[1])), fmaxf(vmax4(za[2]), vmax4(za[3])));
    float tmb = fmaxf(fmaxf(vmax4(zb[0]), vmax4(zb[1])), fmaxf(vmax4(zb[2]), vmax4(zb[3])));
    if (__any((tma > m_a + 8.0f) || (tmb > m_b + 8.0f))) {
      float ta = tma;
      ta = fmaxf(ta, __shfl_xor(ta, 16, 64));
      ta = fmaxf(ta, __shfl_xor(ta, 32, 64));
      float tb = tmb;
      tb = fmaxf(tb, __shfl_xor(tb, 16, 64));
      tb = fmaxf(tb, __shfl_xor(tb, 32, 64));
      float mna = fmaxf(m_a, ta), ala = exp2fast(m_a - mna);
      float mnb = fmaxf(m_b, tb), alb = exp2fast(m_b - mnb);
      m_a = mna; ls_a *= ala;
      m_b = mnb; ls_b *= alb;
#pragma unroll
      for (int d = 0; d < 4; ++d) { oca[d] = oca[d] * ala; ocb[d] = ocb[d] * alb; }
    }

    unsigned int pwa[8], pwb[8];
#pragma unroll
    for (int s = 0; s < 4; ++s) {
      float p0 = exp2fast(za[s][0] - m_a), p1 = exp2fast(za[s][1] - m_a);
      float p2 = exp2fast(za[s][2] - m_a), p3 = exp2fast(za[s][3] - m_a);
      ls_a += (p0 + p1) + (p2 + p3);
      pwa[2 * s] = pack2(p0, p1); pwa[2 * s + 1] = pack2(p2, p3);
      float r0 = exp2fast(zb[s][0] - m_b), r1 = exp2fast(zb[s][1] - m_b);
      float r2 = exp2fast(zb[s][2] - m_b), r3 = exp2fast(zb[s][3] - m_b);
      ls_b += (r0 + r1) + (r2 + r3);
      pwb[2 * s] = pack2(r0, r1); pwb[2 * s + 1] = pack2(r2, r3);
    }
    union { uint4 u; s16x8 v; } c0, c1, c2, c3;
    c0.u = make_uint4(pwa[0], pwa[1], pwa[2], pwa[3]);
    c1.u = make_uint4(pwa[4], pwa[5], pwa[6], pwa[7]);
    c2.u = make_uint4(pwb[0], pwb[1], pwb[2], pwb[3]);
    c3.u = make_uint4(pwb[4], pwb[5], pwb[6], pwb[7]);
    s16x8 pf0a = c0.v, pf1a = c1.v, pf0b = c2.v, pf1b = c3.v;

#pragma unroll
    for (int d = 0; d < 4; ++d) {
      s16x8 v0 = lds_frag(ldsV, d * 16 + ln, g);
      s16x8 v1 = lds_frag(ldsV, d * 16 + ln, 4 + g);
      oca[d] = mfma16(v0, pf0a, oca[d]);
      oca[d] = mfma16(v1, pf1a, oca[d]);
      ocb[d] = mfma16(v0, pf0b, ocb[d]);
      ocb[d] = mfma16(v1, pf1b, ocb[d]);
    }
    __syncthreads();
    cur ^= 1;
  }

  ls_a += __shfl_xor(ls_a, 16, 64);
  ls_a += __shfl_xor(ls_a, 32, 64);
  ls_b += __shfl_xor(ls_b, 16, 64);
  ls_b += __shfl_xor(ls_b, 32, 64);
  float inva = 1.0f / ls_a, invb = 1.0f / ls_b;
  int orow = bb * 2048 + pair * 1024 + q0 + ln;
#pragma unroll
  for (int d = 0; d < 4; ++d) {
    uint2 st;
    st.x = pack2(oca[d][0] * inva, oca[d][1] * inva);
    st.y = pack2(oca[d][2] * inva, oca[d][3] * inva);
    *reinterpret_cast<uint2*>(AO + (size_t)orow * 512 + h * 64 + d * 16 + 4 * g) = st;
    uint2 st2;
    st2.x = pack2(ocb[d][0] * invb, ocb[d][1] * invb);
    st2.y = pack2(ocb[d][2] * invb, ocb[d][3] * invb);
    *reinterpret_cast<uint2*>(AO + (size_t)(orow + 16) * 512 + h * 64 + d * 16 + 4 * g) = st2;
  }
}

// ---------------- output projection GEMM ----------------

__global__ __launch_bounds__(256) void k_gemm_proj(const ushort* __restrict__ AO,
                                                   const ushort* __restrict__ WtP,
                                                   const float* __restrict__ bP,
                                                   float* __restrict__ Out) {
  __shared__ __align__(16) char lds[32768];
  char* ldsA = lds;
  char* ldsB = lds + 16384;
  int m0 = blockIdx.x * 128, n0 = blockIdx.y * 128;
  const ushort* A = AO + (size_t)m0 * 512;
  const ushort* Wt = WtP + (size_t)n0 * 512;
  int t = threadIdx.x;
  int wid = t >> 6, ln = t & 15, g = (t & 63) >> 4;
  int wr = wid >> 1, wc = wid & 1;
  f32x4 acc[4][4] = {};
  for (int ks = 0; ks < 8; ++ks) {
    __syncthreads();
    stage_tile(A + ks * 64, 512, ldsA);
    stage_tile(Wt + ks * 64, 512, ldsB);
    __syncthreads();
#pragma unroll
    for (int kk = 0; kk < 2; ++kk) {
      s16x8 af[4], bf[4];
#pragma unroll
      for (int mi = 0; mi < 4; ++mi) af[mi] = lds_frag(ldsA, wr * 64 + mi * 16 + ln, kk * 4 + g);
#pragma unroll
      for (int ni = 0; ni < 4; ++ni) bf[ni] = lds_frag(ldsB, wc * 64 + ni * 16 + ln, kk * 4 + g);
#pragma unroll
      for (int mi = 0; mi < 4; ++mi)
#pragma unroll
        for (int ni = 0; ni < 4; ++ni) acc[mi][ni] = mfma16(af[mi], bf[ni], acc[mi][ni]);
    }
  }
#pragma unroll
  for (int mi = 0; mi < 4; ++mi)
#pragma unroll
    for (int ni = 0; ni < 4; ++ni) {
      f32x4 v = acc[mi][ni];
      int col = n0 + wc * 64 + ni * 16 + ln;
      float bv = bP[col];
      int r0 = m0 + wr * 64 + mi * 16 + g * 4;
#pragma unroll
      for (int j = 0; j < 4; ++j) Out[(size_t)(r0 + j) * 512 + col] = v[j] + bv;
    }
}

// ---------------- launch ----------------

extern "C" void kernel_launch(void* const* d_in, const int* in_sizes, int n_in,
                              void* d_out, int out_size, void* d_ws, size_t ws_size,
                              hipStream_t stream) {
  const float* x      = (const float*)d_in[0];
  const float* W_rgb  = (const float*)d_in[1];
  const float* b_rgb  = (const float*)d_in[2];
  const float* W_dep  = (const float*)d_in[3];
  const float* b_dep  = (const float*)d_in[4];
  const float* W_proj = (const float*)d_in[5];
  const float* b_proj = (const float*)d_in[6];
  float* out = (float*)d_out;

  char* ws = (char*)d_ws;
  ushort* xb  = (ushort*)(ws + 0);
  ushort* WtR = (ushort*)(ws + 16777216);
  ushort* WtD = (ushort*)(ws + 18350080);
  ushort* WtP = (ushort*)(ws + 19922944);
  ushort* Qb  = (ushort*)(ws + 20447232);
  ushort* Kb  = (ushort*)(ws + 37224448);
  ushort* Vt  = (ushort*)(ws + 54001664);
  ushort* AO  = (ushort*)(ws + 70778880);

  k_cast<<<8192, 256, 0, stream>>>(x, xb, 8388608);
  k_transpose_cast<<<dim3(48, 16), 256, 0, stream>>>(W_rgb, WtR, 512, 1536);
  k_transpose_cast<<<dim3(48, 16), 256, 0, stream>>>(W_dep, WtD, 512, 1536);
  k_transpose_cast<<<dim3(16, 16), 256, 0, stream>>>(W_proj, WtP, 512, 512);
  k_gemm_qkv<false><<<dim3(128, 8), 256, 0, stream>>>(xb, WtR, WtD, b_rgb, b_dep, Qb, Kb, Vt);
  k_gemm_qkv<true><<<dim3(128, 4), 256, 0, stream>>>(xb, WtR, WtD, b_rgb, b_dep, Qb, Kb, Vt);
  k_attn<<<dim3(8, 16, 8), 256, 0, stream>>>(Qb, Kb, Vt, AO);
  k_gemm_proj<<<dim3(128, 4), 256, 0, stream>>>(AO, WtP, b_proj, out);
}